// Round 1
// baseline (7412.695 us; speedup 1.0000x reference)
//
#include <hip/hip_runtime.h>

#define DT_TM 0.1f     // DT * TAU_MEM_INV
#define SYN_DEC 0.8f   // 1 - DT * TAU_SYN_INV
#define TT 16
#define BB 64

// ---------------- ws layout (bytes) ----------------
// s1 : u8  [16][64][32][30][30]            29,491,200
// s2 : u8  [16][64][64][13][13]            11,075,584
// s3 : f32 [16][64][1024]                   4,194,304
// part: f32 [26][64][1024]                  6,815,744
// v2 : f32 [64*1024]                          262,144
// i2 : f32 [64*1024]                          262,144
#define O_S1   ((size_t)0)
#define O_S2   ((size_t)29491200)
#define O_S3   ((size_t)40566784)
#define O_PART ((size_t)44761088)
#define O_V2   ((size_t)51576832)
#define O_I2   ((size_t)51838976)

// ---------------------------------------------------------------------------
// K1: conv1 (3->32, 5x5, VALID, 64->60) + LIF + 2x2 maxpool (spikes), all T.
// block = (oc, b). 256 threads; threads 0..224 each own a 2x2 pooled quad
// (= 4x4 conv pixels, 32 state floats in registers across t).
// ---------------------------------------------------------------------------
__global__ __launch_bounds__(256) void k1_conv1(
    const float* __restrict__ x, const float* __restrict__ w1,
    const float* __restrict__ b1, unsigned char* __restrict__ s1) {
  __shared__ float xs[3 * 64 * 64];
  const int oc = blockIdx.x;
  const int b  = blockIdx.y;
  const int tid = threadIdx.x;
  const int q = tid;
  const bool valid = q < 225;
  const int py0 = (q / 15) * 2;      // pooled row base (0..28)
  const int px0 = (q % 15) * 2;      // pooled col base
  const int br = 2 * py0;            // conv row base (input row base too)
  const int bc = 2 * px0;

  float v[16], cur[16];
#pragma unroll
  for (int j = 0; j < 16; ++j) { v[j] = 0.f; cur[j] = 0.f; }
  const float bias = b1[oc];

  for (int t = 0; t < TT; ++t) {
    const float* xp = x + ((size_t)(t * BB + b)) * 12288;
#pragma unroll
    for (int k = 0; k < 12; ++k) {
      int e = tid + k * 256;
      ((float4*)xs)[e] = ((const float4*)xp)[e];
    }
    __syncthreads();

    if (valid) {
      float acc[4][4];
#pragma unroll
      for (int r = 0; r < 4; ++r)
#pragma unroll
        for (int s = 0; s < 4; ++s) acc[r][s] = 0.f;

#pragma unroll
      for (int c = 0; c < 3; ++c) {
        const float* wp = w1 + (oc * 3 + c) * 25;   // block-uniform -> s_load
        float wv[25];
#pragma unroll
        for (int j = 0; j < 25; ++j) wv[j] = wp[j];
#pragma unroll
        for (int ri = 0; ri < 8; ++ri) {
          const float* rowp = &xs[(c * 64 + br + ri) * 64 + bc];
          float4 ra = *(const float4*)rowp;
          float4 rb = *(const float4*)(rowp + 4);
          float row[8] = {ra.x, ra.y, ra.z, ra.w, rb.x, rb.y, rb.z, rb.w};
#pragma unroll
          for (int r = 0; r < 4; ++r) {
            int ky = ri - r;
            if (ky >= 0 && ky < 5) {
#pragma unroll
              for (int kx = 0; kx < 5; ++kx) {
                float w = wv[ky * 5 + kx];
#pragma unroll
                for (int s = 0; s < 4; ++s) acc[r][s] += w * row[s + kx];
              }
            }
          }
        }
      }

      // LIF + pool (spike uses OLD v,i; input enters i afterward)
      unsigned char pz00 = 0, pz01 = 0, pz10 = 0, pz11 = 0;
#pragma unroll
      for (int r = 0; r < 4; ++r)
#pragma unroll
        for (int s = 0; s < 4; ++s) {
          int j = r * 4 + s;
          float vd = v[j] + DT_TM * (cur[j] - v[j]);
          float id = SYN_DEC * cur[j];
          float inp = acc[r][s] + bias;
          bool z = vd > 1.0f;
          v[j] = z ? 0.f : vd;
          cur[j] = id + inp;
          if (z) {
            if (r < 2) { if (s < 2) pz00 = 1; else pz01 = 1; }
            else       { if (s < 2) pz10 = 1; else pz11 = 1; }
          }
        }
      size_t base = ((size_t)((t * BB + b) * 32 + oc)) * 900;
      *(uchar2*)&s1[base + (size_t)py0 * 30 + px0]       = make_uchar2(pz00, pz01);
      *(uchar2*)&s1[base + (size_t)(py0 + 1) * 30 + px0] = make_uchar2(pz10, pz11);
    }
    __syncthreads();
  }
}

// ---------------------------------------------------------------------------
// K2: conv2 (32->64, 5x5, 30->26) *10 + LIF + pool -> 13x13 spikes, all T.
// grid = (ocgrp 16, chunk 3, b 64). 256 threads = 4 oc x 64 pooled slots.
// s1 tile (u8 -> f32) staged in LDS per t, shared by the 4 oc.
// Weights read as wave-uniform scalar loads (oc forced uniform).
// ---------------------------------------------------------------------------
__global__ __launch_bounds__(256) void k2_conv2(
    const unsigned char* __restrict__ s1, const float* __restrict__ w2,
    const float* __restrict__ b2, unsigned char* __restrict__ s2) {
  __shared__ float ls[32 * 16 * 30];
  const int ocg = blockIdx.x;
  const int chunk = blockIdx.y;
  const int b = blockIdx.z;
  const int tid = threadIdx.x;
  const int ocsub = __builtin_amdgcn_readfirstlane(tid >> 6);
  const int oc = ocg * 4 + ocsub;
  const int q = tid & 63;
  const int idx = chunk * 64 + q;          // pooled linear index 0..168
  const bool valid = idx < 169;
  const int y = idx / 13;
  const int xx = idx - y * 13;
  const int r0 = (chunk == 0) ? 0 : ((chunk == 1) ? 8 : 18);
  const int lrbase = 2 * y - r0;

  float v[4] = {0.f, 0.f, 0.f, 0.f}, cur[4] = {0.f, 0.f, 0.f, 0.f};
  const float bias = b2[oc];

  for (int t = 0; t < TT; ++t) {
    const unsigned char* sp = s1 + ((size_t)((t * BB + b) * 32)) * 900;
    for (int k = 0; k < 60; ++k) {
      int e = tid + k * 256;
      int c = e / 480;
      int rem = e - c * 480;
      int r = rem / 30;
      int col = rem - r * 30;
      int gr = r0 + r;
      float val = 0.f;
      if (gr < 30) val = (float)sp[c * 900 + gr * 30 + col];
      ls[(c * 16 + r) * 30 + col] = val;
    }
    __syncthreads();

    if (valid) {
      float acc[4] = {0.f, 0.f, 0.f, 0.f};   // [dy*2+dx]
#pragma unroll
      for (int c = 0; c < 32; ++c) {
        const float* wp = w2 + ((oc * 32) + c) * 25;   // wave-uniform -> s_load
        float wv[25];
#pragma unroll
        for (int j = 0; j < 25; ++j) wv[j] = wp[j];
#pragma unroll
        for (int ri = 0; ri < 6; ++ri) {
          const float* rp = &ls[(c * 16 + lrbase + ri) * 30 + 2 * xx];
          float row[6];
#pragma unroll
          for (int j = 0; j < 6; ++j) row[j] = rp[j];
#pragma unroll
          for (int dy = 0; dy < 2; ++dy) {
            int ky = ri - dy;
            if (ky >= 0 && ky < 5) {
#pragma unroll
              for (int kx = 0; kx < 5; ++kx) {
                float w = wv[ky * 5 + kx];
                acc[dy * 2 + 0] += w * row[kx];
                acc[dy * 2 + 1] += w * row[kx + 1];
              }
            }
          }
        }
      }
      unsigned char pooled = 0;
#pragma unroll
      for (int j = 0; j < 4; ++j) {
        float vd = v[j] + DT_TM * (cur[j] - v[j]);
        float id = SYN_DEC * cur[j];
        float inp = 10.0f * (acc[j] + bias);
        bool z = vd > 1.0f;
        v[j] = z ? 0.f : vd;
        cur[j] = id + inp;
        if (z) pooled = 1;
      }
      s2[((size_t)((t * BB + b) * 64 + oc)) * 169 + (size_t)(y * 13 + xx)] = pooled;
    }
    __syncthreads();
  }
}

// ---------------------------------------------------------------------------
// K3a: FC GEMM partials for one t: z(64x10816,u8 spikes) @ wf^T -> 64x1024.
// grid = (ntile 16, ksplit 26); block 64x64 tile over K-chunk 416.
// ---------------------------------------------------------------------------
__global__ __launch_bounds__(256) void k3a_fc(
    const unsigned char* __restrict__ s2, const float* __restrict__ wf,
    float* __restrict__ part, int t) {
  __shared__ float As[16][68];
  __shared__ float Bs[16][68];
  const int nt = blockIdx.x;
  const int ks = blockIdx.y;
  const int tid = threadIdx.x;
  const int N0 = nt * 64;
  const int kbase = ks * 416;
  const unsigned char* A = s2 + (size_t)t * BB * 10816;

  const int lm = tid >> 2;       // 0..63
  const int kq = tid & 3;        // 0..3
  const int m0 = (tid >> 4) << 2;
  const int n0 = (tid & 15) << 2;

  float acc[4][4];
#pragma unroll
  for (int i = 0; i < 4; ++i)
#pragma unroll
    for (int j = 0; j < 4; ++j) acc[i][j] = 0.f;

  for (int step = 0; step < 26; ++step) {
    int k0 = kbase + step * 16;
    uchar4 a4 = *(const uchar4*)&A[(size_t)lm * 10816 + k0 + kq * 4];
    float4 b4 = *(const float4*)&wf[(size_t)(N0 + lm) * 10816 + k0 + kq * 4];
    __syncthreads();
    As[kq * 4 + 0][lm] = (float)a4.x;
    As[kq * 4 + 1][lm] = (float)a4.y;
    As[kq * 4 + 2][lm] = (float)a4.z;
    As[kq * 4 + 3][lm] = (float)a4.w;
    Bs[kq * 4 + 0][lm] = b4.x;
    Bs[kq * 4 + 1][lm] = b4.y;
    Bs[kq * 4 + 2][lm] = b4.z;
    Bs[kq * 4 + 3][lm] = b4.w;
    __syncthreads();
#pragma unroll
    for (int kk = 0; kk < 16; ++kk) {
      float4 av = *(const float4*)&As[kk][m0];
      float4 bv = *(const float4*)&Bs[kk][n0];
      float a0 = av.x, a1 = av.y, a2 = av.z, a3 = av.w;
      acc[0][0] += a0 * bv.x; acc[0][1] += a0 * bv.y; acc[0][2] += a0 * bv.z; acc[0][3] += a0 * bv.w;
      acc[1][0] += a1 * bv.x; acc[1][1] += a1 * bv.y; acc[1][2] += a1 * bv.z; acc[1][3] += a1 * bv.w;
      acc[2][0] += a2 * bv.x; acc[2][1] += a2 * bv.y; acc[2][2] += a2 * bv.z; acc[2][3] += a2 * bv.w;
      acc[3][0] += a3 * bv.x; acc[3][1] += a3 * bv.y; acc[3][2] += a3 * bv.z; acc[3][3] += a3 * bv.w;
    }
  }
#pragma unroll
  for (int i = 0; i < 4; ++i)
#pragma unroll
    for (int j = 0; j < 4; ++j)
      part[((size_t)(ks * 64 + m0 + i)) * 1024 + N0 + n0 + j] = acc[i][j];
}

// ---------------------------------------------------------------------------
// K3b: deterministic split-K reduce + bias + LIF2 (states in ws) -> s3[t]
// ---------------------------------------------------------------------------
__global__ __launch_bounds__(256) void k3b_lif2(
    const float* __restrict__ part, const float* __restrict__ bf,
    float* __restrict__ v2, float* __restrict__ i2,
    float* __restrict__ s3, int t) {
  int e = blockIdx.x * 256 + threadIdx.x;   // 0..65535
  int n = e & 1023;
  float s = 0.f;
#pragma unroll
  for (int ks = 0; ks < 26; ++ks) s += part[(size_t)ks * 65536 + e];
  float z = s + bf[n];
  float vv = v2[e], ii = i2[e];
  float vd = vv + DT_TM * (ii - vv);
  float id = SYN_DEC * ii;
  bool sp = vd > 1.0f;
  v2[e] = sp ? 0.f : vd;
  i2[e] = id + z;
  s3[(size_t)t * 65536 + e] = sp ? 1.f : 0.f;
}

// ---------------------------------------------------------------------------
// K4: readout. block per b; 10 groups x 32 lanes; LI state in registers
// (lane 0 of each group holds the true state). Writes voltages [T][B][10].
// ---------------------------------------------------------------------------
__global__ __launch_bounds__(320) void k4_out(
    const float* __restrict__ s3, const float* __restrict__ wo,
    const float* __restrict__ bo, float* __restrict__ out) {
  const int b = blockIdx.x;
  const int g = threadIdx.x >> 5;
  const int l = threadIdx.x & 31;
  float vv = 0.f, ii = 0.f;
  const float bg = bo[g];
  for (int t = 0; t < TT; ++t) {
    const float* zp = s3 + ((size_t)t * BB + b) * 1024;
    const float* wp = wo + g * 1024;
    float p = 0.f;
#pragma unroll 8
    for (int j = l; j < 1024; j += 32) p += zp[j] * wp[j];
#pragma unroll
    for (int off = 16; off; off >>= 1) p += __shfl_down(p, off, 32);
    float inp = p + bg;                 // only lane 0's is complete
    float vn = vv + DT_TM * (ii - vv);  // uses OLD i
    if (l == 0) out[(size_t)(t * BB + b) * 10 + g] = vn;
    ii = SYN_DEC * ii + inp;
    vv = vn;
  }
}

extern "C" void kernel_launch(void* const* d_in, const int* in_sizes, int n_in,
                              void* d_out, int out_size, void* d_ws, size_t ws_size,
                              hipStream_t stream) {
  (void)in_sizes; (void)n_in; (void)out_size; (void)ws_size;
  const float* x  = (const float*)d_in[0];
  const float* w1 = (const float*)d_in[1];
  const float* b1 = (const float*)d_in[2];
  const float* w2 = (const float*)d_in[3];
  const float* b2 = (const float*)d_in[4];
  const float* wf = (const float*)d_in[5];
  const float* bf = (const float*)d_in[6];
  const float* wo = (const float*)d_in[7];
  const float* bo = (const float*)d_in[8];
  float* out = (float*)d_out;
  char* ws = (char*)d_ws;

  unsigned char* s1 = (unsigned char*)(ws + O_S1);
  unsigned char* s2 = (unsigned char*)(ws + O_S2);
  float* s3   = (float*)(ws + O_S3);
  float* part = (float*)(ws + O_PART);
  float* v2   = (float*)(ws + O_V2);
  float* i2   = (float*)(ws + O_I2);

  // zero LIF2 state (v2 and i2 are contiguous)
  hipMemsetAsync(v2, 0, 2 * 65536 * sizeof(float), stream);

  k1_conv1<<<dim3(32, 64), 256, 0, stream>>>(x, w1, b1, s1);
  k2_conv2<<<dim3(16, 3, 64), 256, 0, stream>>>(s1, w2, b2, s2);
  for (int t = 0; t < TT; ++t) {
    k3a_fc<<<dim3(16, 26), 256, 0, stream>>>(s2, wf, part, t);
    k3b_lif2<<<dim3(256), 256, 0, stream>>>(part, bf, v2, i2, s3, t);
  }
  k4_out<<<dim3(64), 320, 0, stream>>>(s3, wo, bo, out);
}

// Round 2
// 1153.585 us; speedup vs baseline: 6.4258x; 6.4258x over previous
//
#include <hip/hip_runtime.h>

typedef __attribute__((ext_vector_type(8))) short short8v;
typedef __attribute__((ext_vector_type(4))) float f32x4;

#define DT_TM 0.1f     // DT * TAU_MEM_INV
#define SYN_DEC 0.8f   // 1 - DT * TAU_SYN_INV
#define TT 16
#define BB 64

// ---------------- ws layout (bytes) ----------------
// s1 : u8  [16][64][900pix][32c]  (channel-last!)   29,491,200
// s2 : u8  [16][64][64][169]                        11,075,584
// s3 : f32 [16][64][1024]                            4,194,304
// part: f32 [26][64][1024]                           6,815,744
// v2/i2 : f32 [64*1024] each
// whi/wlo (bf16 split weights) ALIAS part: written by k0 before k2,
// consumed only by k2; part first written by k3a (after k2). Safe.
#define O_S1   ((size_t)0)
#define O_S2   ((size_t)29491200)
#define O_S3   ((size_t)40566784)
#define O_PART ((size_t)44761088)
#define O_V2   ((size_t)51576832)
#define O_I2   ((size_t)51838976)
#define O_WH   O_PART
#define O_WL   (O_PART + 102400)

// ---------------------------------------------------------------------------
// K0: split conv2 weights into bf16 hi/lo pairs, layout [kk 25][oc 64][c 32]
// ---------------------------------------------------------------------------
__device__ __forceinline__ unsigned short bf16_rne(float f) {
  unsigned int u = __float_as_uint(f);
  return (unsigned short)((u + 0x7FFFu + ((u >> 16) & 1u)) >> 16);
}

__global__ __launch_bounds__(256) void k0_prep(
    const float* __restrict__ w2, unsigned short* __restrict__ whi,
    unsigned short* __restrict__ wlo) {
  int e = blockIdx.x * 256 + threadIdx.x;
  if (e >= 25 * 64 * 32) return;
  int kk = e >> 11;              // 0..24
  int rem = e & 2047;
  int oc = rem >> 5, c = rem & 31;
  float w = w2[(size_t)(oc * 32 + c) * 25 + kk];
  unsigned short hi = bf16_rne(w);
  float fhi = __uint_as_float((unsigned int)hi << 16);
  unsigned short lo = bf16_rne(w - fhi);
  whi[e] = hi;
  wlo[e] = lo;
}

// ---------------------------------------------------------------------------
// K1: conv1 (3->32, 5x5, 64->60) + LIF + 2x2 maxpool -> spikes, all T.
// Writes s1 channel-last: s1[((t*64+b)*900 + py*30+px)*32 + oc]
// ---------------------------------------------------------------------------
__global__ __launch_bounds__(256) void k1_conv1(
    const float* __restrict__ x, const float* __restrict__ w1,
    const float* __restrict__ b1, unsigned char* __restrict__ s1) {
  __shared__ float xs[3 * 64 * 64];
  const int oc = blockIdx.x;
  const int b  = blockIdx.y;
  const int tid = threadIdx.x;
  const bool valid = tid < 225;
  const int py0 = (tid / 15) * 2;
  const int px0 = (tid % 15) * 2;
  const int br = 2 * py0;
  const int bc = 2 * px0;

  float v[16], cur[16];
#pragma unroll
  for (int j = 0; j < 16; ++j) { v[j] = 0.f; cur[j] = 0.f; }
  const float bias = b1[oc];

  for (int t = 0; t < TT; ++t) {
    const float* xp = x + ((size_t)(t * BB + b)) * 12288;
#pragma unroll
    for (int k = 0; k < 12; ++k) {
      int e = tid + k * 256;
      ((float4*)xs)[e] = ((const float4*)xp)[e];
    }
    __syncthreads();

    if (valid) {
      float acc[4][4];
#pragma unroll
      for (int r = 0; r < 4; ++r)
#pragma unroll
        for (int s = 0; s < 4; ++s) acc[r][s] = 0.f;

#pragma unroll
      for (int c = 0; c < 3; ++c) {
        const float* wp = w1 + (oc * 3 + c) * 25;
        float wv[25];
#pragma unroll
        for (int j = 0; j < 25; ++j) wv[j] = wp[j];
#pragma unroll
        for (int ri = 0; ri < 8; ++ri) {
          const float* rowp = &xs[(c * 64 + br + ri) * 64 + bc];
          float4 ra = *(const float4*)rowp;
          float4 rb = *(const float4*)(rowp + 4);
          float row[8] = {ra.x, ra.y, ra.z, ra.w, rb.x, rb.y, rb.z, rb.w};
#pragma unroll
          for (int r = 0; r < 4; ++r) {
            int ky = ri - r;
            if (ky >= 0 && ky < 5) {
#pragma unroll
              for (int kx = 0; kx < 5; ++kx) {
                float w = wv[ky * 5 + kx];
#pragma unroll
                for (int s = 0; s < 4; ++s) acc[r][s] += w * row[s + kx];
              }
            }
          }
        }
      }

      unsigned char pz00 = 0, pz01 = 0, pz10 = 0, pz11 = 0;
#pragma unroll
      for (int r = 0; r < 4; ++r)
#pragma unroll
        for (int s = 0; s < 4; ++s) {
          int j = r * 4 + s;
          float vd = v[j] + DT_TM * (cur[j] - v[j]);
          float id = SYN_DEC * cur[j];
          float inp = acc[r][s] + bias;
          bool z = vd > 1.0f;
          v[j] = z ? 0.f : vd;
          cur[j] = id + inp;
          if (z) {
            if (r < 2) { if (s < 2) pz00 = 1; else pz01 = 1; }
            else       { if (s < 2) pz10 = 1; else pz11 = 1; }
          }
        }
      size_t pixb = ((size_t)(t * BB + b)) * 900;
      s1[(pixb + (size_t)py0 * 30 + px0) * 32 + oc]           = pz00;
      s1[(pixb + (size_t)py0 * 30 + px0 + 1) * 32 + oc]       = pz01;
      s1[(pixb + (size_t)(py0 + 1) * 30 + px0) * 32 + oc]     = pz10;
      s1[(pixb + (size_t)(py0 + 1) * 30 + px0 + 1) * 32 + oc] = pz11;
    }
    __syncthreads();
  }
}

// ---------------------------------------------------------------------------
// K2: conv2 via MFMA (bf16 hi/lo split) + *10 + LIF + 2x2 pool, all T.
// grid (4 quads, 64 b), 256 thr = 4 waves = 2 oc-halves x 2 pos-chunks.
// Quad q owns conv rows: {0..7, 8..13, 14..19, 20..25} (pool-pair aligned).
// Spikes bf16 in LDS (channel-last); LIF state in LDS (stride 68 = no
// bank conflict on float4); zbuf for cross-wave 2x2 pooling.
// MFMA 16x16x32: A = weights[oc16 x c32] (m=lane&15 -> oc, k=(lane>>4)*8+i
// -> c), B = spikes[c32 x pos16] (n=lane&15 -> pos), D rows=(lane>>4)*4+reg.
// ---------------------------------------------------------------------------
template<int NT>
__device__ __forceinline__ void k2_wave(
    const unsigned short* sl, float* Vst, float* Ist, unsigned char* zbuf,
    const unsigned short* __restrict__ whi, const unsigned short* __restrict__ wlo,
    const float* __restrict__ b2, int og, int q, int n, int ntstart, int npos) {
  int baddr[NT], pcl[NT];
  f32x4 acc[2][NT];
#pragma unroll
  for (int j = 0; j < NT; ++j) {
    int pl = (ntstart + j) * 16 + n;
    if (pl > npos - 1) pl = npos - 1;   // tail lanes duplicate last pos
    pcl[j] = pl;
    int ry = pl / 26, xx = pl - ry * 26;
    baddr[j] = (ry * 30 + xx) * 32 + q * 8;
    acc[0][j] = (f32x4){0.f, 0.f, 0.f, 0.f};
    acc[1][j] = (f32x4){0.f, 0.f, 0.f, 0.f};
  }
  const int abase = (og * 32 + n) * 32 + q * 8;  // + mi*512 + kk*2048
#pragma unroll 5
  for (int kk = 0; kk < 25; ++kk) {
    const int ky = kk / 5, kx = kk - (kk / 5) * 5;
    const int off = (ky * 30 + kx) * 32;
    short8v ah0 = *(const short8v*)(whi + kk * 2048 + abase);
    short8v al0 = *(const short8v*)(wlo + kk * 2048 + abase);
    short8v ah1 = *(const short8v*)(whi + kk * 2048 + abase + 512);
    short8v al1 = *(const short8v*)(wlo + kk * 2048 + abase + 512);
#pragma unroll
    for (int j = 0; j < NT; ++j) {
      short8v bv = *(const short8v*)(sl + baddr[j] + off);
      acc[0][j] = __builtin_amdgcn_mfma_f32_16x16x32_bf16(al0, bv, acc[0][j], 0, 0, 0);
      acc[0][j] = __builtin_amdgcn_mfma_f32_16x16x32_bf16(ah0, bv, acc[0][j], 0, 0, 0);
      acc[1][j] = __builtin_amdgcn_mfma_f32_16x16x32_bf16(al1, bv, acc[1][j], 0, 0, 0);
      acc[1][j] = __builtin_amdgcn_mfma_f32_16x16x32_bf16(ah1, bv, acc[1][j], 0, 0, 0);
    }
  }
  // LIF + state update + spike record
  const f32x4 bias0 = *(const f32x4*)&b2[og * 32 + q * 4];
  const f32x4 bias1 = *(const f32x4*)&b2[og * 32 + 16 + q * 4];
#pragma unroll
  for (int j = 0; j < NT; ++j) {
    int p = pcl[j];
#pragma unroll
    for (int mi = 0; mi < 2; ++mi) {
      int sidx = p * 68 + og * 32 + mi * 16 + q * 4;
      f32x4 v4 = *(f32x4*)&Vst[sidx];
      f32x4 i4 = *(f32x4*)&Ist[sidx];
      f32x4 bia = mi ? bias1 : bias0;
      f32x4 a = acc[mi][j];
      unsigned char zr[4];
#pragma unroll
      for (int r = 0; r < 4; ++r) {
        float vd = v4[r] + DT_TM * (i4[r] - v4[r]);
        float id = SYN_DEC * i4[r];
        float inp = 10.f * (a[r] + bia[r]);
        bool z = vd > 1.0f;
        v4[r] = z ? 0.f : vd;
        i4[r] = id + inp;
        zr[r] = z ? 1 : 0;
      }
      *(f32x4*)&Vst[sidx] = v4;
      *(f32x4*)&Ist[sidx] = i4;
      *(uchar4*)&zbuf[sidx] = make_uchar4(zr[0], zr[1], zr[2], zr[3]);
    }
  }
}

__global__ __launch_bounds__(256) void k2_mfma(
    const unsigned char* __restrict__ s1, const unsigned short* __restrict__ whi,
    const unsigned short* __restrict__ wlo, const float* __restrict__ b2,
    unsigned char* __restrict__ s2) {
  __shared__ unsigned short sl[12 * 30 * 32];   // 23,040 B spikes bf16
  __shared__ float Vst[208 * 68];               // 56,576 B
  __shared__ float Ist[208 * 68];               // 56,576 B
  __shared__ unsigned char zbuf[208 * 68];      // 14,144 B  (total 150,336)
  const int quad = blockIdx.x, b = blockIdx.y;
  const int tid = threadIdx.x;
  const int wid = tid >> 6, l = tid & 63;
  const int og = wid & 1, nc = wid >> 1;
  const int q = l >> 4, n = l & 15;
  const int y0 = (quad == 0) ? 0 : (2 + quad * 6);   // 0,8,14,20
  const int R  = (quad == 0) ? 8 : 6;                 // conv rows owned
  const int inRows = R + 4;
  const int npos = R * 26;

  for (int e = tid; e < 208 * 68; e += 256) { Vst[e] = 0.f; Ist[e] = 0.f; }
  __syncthreads();

  for (int t = 0; t < TT; ++t) {
    // ---- stage spikes u8 -> bf16, channel-last, linear ----
    const unsigned char* sp =
        s1 + (((size_t)(t * BB + b)) * 900 + (size_t)y0 * 30) * 32;
    const int nelem = inRows * 240;   // uint count (8 uints per pixel)
    for (int e = tid; e < nelem; e += 256) {
      unsigned int w = *(const unsigned int*)(sp + (size_t)e * 4);
      unsigned int lo = ((w & 0xFFu) ? 0x3F80u : 0u) |
                        ((w & 0xFF00u) ? 0x3F800000u : 0u);
      unsigned int hi = ((w & 0xFF0000u) ? 0x3F80u : 0u) |
                        ((w & 0xFF000000u) ? 0x3F800000u : 0u);
      ((unsigned int*)sl)[e * 2]     = lo;
      ((unsigned int*)sl)[e * 2 + 1] = hi;
    }
    __syncthreads();

    // ---- MFMA conv + LIF ----
    if (quad == 0) {
      if (nc == 0) k2_wave<7>(sl, Vst, Ist, zbuf, whi, wlo, b2, og, q, n, 0, npos);
      else         k2_wave<6>(sl, Vst, Ist, zbuf, whi, wlo, b2, og, q, n, 7, npos);
    } else {
      k2_wave<5>(sl, Vst, Ist, zbuf, whi, wlo, b2, og, q, n, nc * 5, npos);
    }
    __syncthreads();

    // ---- 2x2 pool (OR) + write s2 [t][b][oc][169] ----
    const int pr = R >> 1;
    const int pcount = pr * 13 * 64;
    unsigned char* s2p = s2 + ((size_t)(t * BB + b)) * 64 * 169;
    const int gpy0 = y0 >> 1;
    for (int e = tid; e < pcount; e += 256) {
      int oc = e & 63, pp = e >> 6;
      int ppy = pp / 13, ppx = pp - ppy * 13;
      int base = (2 * ppy * 26 + 2 * ppx) * 68 + oc;
      unsigned char z = (unsigned char)(zbuf[base] | zbuf[base + 68] |
                        zbuf[base + 26 * 68] | zbuf[base + 26 * 68 + 68]);
      s2p[(size_t)oc * 169 + (gpy0 + ppy) * 13 + ppx] = z;
    }
    __syncthreads();
  }
}

// ---------------------------------------------------------------------------
// K3a: FC GEMM partials for one t: z(64x10816 u8) @ wf^T -> part[26][64][1024]
// ---------------------------------------------------------------------------
__global__ __launch_bounds__(256) void k3a_fc(
    const unsigned char* __restrict__ s2, const float* __restrict__ wf,
    float* __restrict__ part, int t) {
  __shared__ float As[16][68];
  __shared__ float Bs[16][68];
  const int nt = blockIdx.x;
  const int ks = blockIdx.y;
  const int tid = threadIdx.x;
  const int N0 = nt * 64;
  const int kbase = ks * 416;
  const unsigned char* A = s2 + (size_t)t * BB * 10816;

  const int lm = tid >> 2;
  const int kq = tid & 3;
  const int m0 = (tid >> 4) << 2;
  const int n0 = (tid & 15) << 2;

  float acc[4][4];
#pragma unroll
  for (int i = 0; i < 4; ++i)
#pragma unroll
    for (int j = 0; j < 4; ++j) acc[i][j] = 0.f;

  for (int step = 0; step < 26; ++step) {
    int k0 = kbase + step * 16;
    uchar4 a4 = *(const uchar4*)&A[(size_t)lm * 10816 + k0 + kq * 4];
    float4 b4 = *(const float4*)&wf[(size_t)(N0 + lm) * 10816 + k0 + kq * 4];
    __syncthreads();
    As[kq * 4 + 0][lm] = (float)a4.x;
    As[kq * 4 + 1][lm] = (float)a4.y;
    As[kq * 4 + 2][lm] = (float)a4.z;
    As[kq * 4 + 3][lm] = (float)a4.w;
    Bs[kq * 4 + 0][lm] = b4.x;
    Bs[kq * 4 + 1][lm] = b4.y;
    Bs[kq * 4 + 2][lm] = b4.z;
    Bs[kq * 4 + 3][lm] = b4.w;
    __syncthreads();
#pragma unroll
    for (int kk = 0; kk < 16; ++kk) {
      float4 av = *(const float4*)&As[kk][m0];
      float4 bv = *(const float4*)&Bs[kk][n0];
      float a0 = av.x, a1 = av.y, a2 = av.z, a3 = av.w;
      acc[0][0] += a0 * bv.x; acc[0][1] += a0 * bv.y; acc[0][2] += a0 * bv.z; acc[0][3] += a0 * bv.w;
      acc[1][0] += a1 * bv.x; acc[1][1] += a1 * bv.y; acc[1][2] += a1 * bv.z; acc[1][3] += a1 * bv.w;
      acc[2][0] += a2 * bv.x; acc[2][1] += a2 * bv.y; acc[2][2] += a2 * bv.z; acc[2][3] += a2 * bv.w;
      acc[3][0] += a3 * bv.x; acc[3][1] += a3 * bv.y; acc[3][2] += a3 * bv.z; acc[3][3] += a3 * bv.w;
    }
  }
#pragma unroll
  for (int i = 0; i < 4; ++i)
#pragma unroll
    for (int j = 0; j < 4; ++j)
      part[((size_t)(ks * 64 + m0 + i)) * 1024 + N0 + n0 + j] = acc[i][j];
}

// ---------------------------------------------------------------------------
// K3b: deterministic split-K reduce + bias + LIF2 -> s3[t]
// ---------------------------------------------------------------------------
__global__ __launch_bounds__(256) void k3b_lif2(
    const float* __restrict__ part, const float* __restrict__ bf,
    float* __restrict__ v2, float* __restrict__ i2,
    float* __restrict__ s3, int t) {
  int e = blockIdx.x * 256 + threadIdx.x;
  int n = e & 1023;
  float s = 0.f;
#pragma unroll
  for (int ks = 0; ks < 26; ++ks) s += part[(size_t)ks * 65536 + e];
  float z = s + bf[n];
  float vv = v2[e], ii = i2[e];
  float vd = vv + DT_TM * (ii - vv);
  float id = SYN_DEC * ii;
  bool sp = vd > 1.0f;
  v2[e] = sp ? 0.f : vd;
  i2[e] = id + z;
  s3[(size_t)t * 65536 + e] = sp ? 1.f : 0.f;
}

// ---------------------------------------------------------------------------
// K4: readout, LI state in registers. out[t][b][10]
// ---------------------------------------------------------------------------
__global__ __launch_bounds__(320) void k4_out(
    const float* __restrict__ s3, const float* __restrict__ wo,
    const float* __restrict__ bo, float* __restrict__ out) {
  const int b = blockIdx.x;
  const int g = threadIdx.x >> 5;
  const int l = threadIdx.x & 31;
  float vv = 0.f, ii = 0.f;
  const float bg = bo[g];
  for (int t = 0; t < TT; ++t) {
    const float* zp = s3 + ((size_t)t * BB + b) * 1024;
    const float* wp = wo + g * 1024;
    float p = 0.f;
#pragma unroll 8
    for (int j = l; j < 1024; j += 32) p += zp[j] * wp[j];
#pragma unroll
    for (int off = 16; off; off >>= 1) p += __shfl_down(p, off, 32);
    float inp = p + bg;
    float vn = vv + DT_TM * (ii - vv);
    if (l == 0) out[(size_t)(t * BB + b) * 10 + g] = vn;
    ii = SYN_DEC * ii + inp;
    vv = vn;
  }
}

extern "C" void kernel_launch(void* const* d_in, const int* in_sizes, int n_in,
                              void* d_out, int out_size, void* d_ws, size_t ws_size,
                              hipStream_t stream) {
  (void)in_sizes; (void)n_in; (void)out_size; (void)ws_size;
  const float* x  = (const float*)d_in[0];
  const float* w1 = (const float*)d_in[1];
  const float* b1 = (const float*)d_in[2];
  const float* w2 = (const float*)d_in[3];
  const float* b2 = (const float*)d_in[4];
  const float* wf = (const float*)d_in[5];
  const float* bf = (const float*)d_in[6];
  const float* wo = (const float*)d_in[7];
  const float* bo = (const float*)d_in[8];
  float* out = (float*)d_out;
  char* ws = (char*)d_ws;

  unsigned char* s1 = (unsigned char*)(ws + O_S1);
  unsigned char* s2 = (unsigned char*)(ws + O_S2);
  float* s3   = (float*)(ws + O_S3);
  float* part = (float*)(ws + O_PART);
  float* v2   = (float*)(ws + O_V2);
  float* i2   = (float*)(ws + O_I2);
  unsigned short* whi = (unsigned short*)(ws + O_WH);
  unsigned short* wlo = (unsigned short*)(ws + O_WL);

  hipMemsetAsync(v2, 0, 2 * 65536 * sizeof(float), stream);

  k0_prep<<<dim3(200), 256, 0, stream>>>(w2, whi, wlo);
  k1_conv1<<<dim3(32, 64), 256, 0, stream>>>(x, w1, b1, s1);
  k2_mfma<<<dim3(4, 64), 256, 0, stream>>>(s1, whi, wlo, b2, s2);
  for (int t = 0; t < TT; ++t) {
    k3a_fc<<<dim3(16, 26), 256, 0, stream>>>(s2, wf, part, t);
    k3b_lif2<<<dim3(256), 256, 0, stream>>>(part, bf, v2, i2, s3, t);
  }
  k4_out<<<dim3(64), 320, 0, stream>>>(s3, wo, bo, out);
}

// Round 3
// 746.052 us; speedup vs baseline: 9.9359x; 1.5463x over previous
//
#include <hip/hip_runtime.h>

typedef __attribute__((ext_vector_type(8))) short short8v;
typedef __attribute__((ext_vector_type(4))) float f32x4;

#define DT_TM 0.1f     // DT * TAU_MEM_INV
#define SYN_DEC 0.8f   // 1 - DT * TAU_SYN_INV
#define TT 16
#define BB 64
#define FCK 10816

// ---------------- ws layout, BIG path (bytes) ----------------
// s1  : u8  [16][64][900pix][32c]            29,491,200
// s2  : bf16[1024 rows=t*64+b][10816]        22,151,168
// s3  : f32 [16][64][1024]                    4,194,304
// part: f32 [4][1024][1024]                  16,777,216   (wh2/wl2 alias head)
// whiF/wloF: bf16 [1024][10816]              22,151,168 each
#define BO_S1   ((size_t)0)
#define BO_S2   ((size_t)29491200)
#define BO_S3   ((size_t)51642368)
#define BO_PART ((size_t)55836672)
#define BO_WH2  BO_PART
#define BO_WL2  (BO_PART + 102400)
#define BO_WHF  ((size_t)72613888)
#define BO_WLF  ((size_t)94765056)
#define BIG_NEED ((size_t)116916224)

// ---------------- ws layout, FALLBACK path (= R2 exactly) ----------------
#define FO_S1   ((size_t)0)
#define FO_S2   ((size_t)29491200)
#define FO_S3   ((size_t)40566784)
#define FO_PART ((size_t)44761088)
#define FO_V2   ((size_t)51576832)
#define FO_I2   ((size_t)51838976)
#define FO_WH2  FO_PART
#define FO_WL2  (FO_PART + 102400)

// ---------------------------------------------------------------------------
__device__ __forceinline__ unsigned short bf16_rne(float f) {
  unsigned int u = __float_as_uint(f);
  return (unsigned short)((u + 0x7FFFu + ((u >> 16) & 1u)) >> 16);
}

// K0a: split conv2 weights into bf16 hi/lo, layout [kk 25][oc 64][c 32]
__global__ __launch_bounds__(256) void k0_prep(
    const float* __restrict__ w2, unsigned short* __restrict__ whi,
    unsigned short* __restrict__ wlo) {
  int e = blockIdx.x * 256 + threadIdx.x;
  if (e >= 25 * 64 * 32) return;
  int kk = e >> 11;
  int rem = e & 2047;
  int oc = rem >> 5, c = rem & 31;
  float w = w2[(size_t)(oc * 32 + c) * 25 + kk];
  unsigned short hi = bf16_rne(w);
  float fhi = __uint_as_float((unsigned int)hi << 16);
  unsigned short lo = bf16_rne(w - fhi);
  whi[e] = hi;
  wlo[e] = lo;
}

// K0b: split wf into bf16 hi/lo, same [n][k] layout (elementwise)
__global__ __launch_bounds__(256) void k0b_wf(
    const float* __restrict__ wf, unsigned short* __restrict__ whiF,
    unsigned short* __restrict__ wloF) {
  size_t e = (size_t)blockIdx.x * 256 + threadIdx.x;
  if (e >= (size_t)1024 * FCK) return;
  float w = wf[e];
  unsigned short hi = bf16_rne(w);
  float fhi = __uint_as_float((unsigned int)hi << 16);
  whiF[e] = hi;
  wloF[e] = bf16_rne(w - fhi);
}

// ---------------------------------------------------------------------------
// K1: conv1 (3->32, 5x5, 64->60) + LIF + 2x2 maxpool -> spikes, all T.
// xs row stride padded 64 -> 68 floats: kills the ~4-way ds_read bank
// conflict (row phase advances 8 banks per 2-row step; 16B align kept).
// ---------------------------------------------------------------------------
__global__ __launch_bounds__(256) void k1_conv1(
    const float* __restrict__ x, const float* __restrict__ w1,
    const float* __restrict__ b1, unsigned char* __restrict__ s1) {
  __shared__ float xs[3 * 64 * 68];
  const int oc = blockIdx.x;
  const int b  = blockIdx.y;
  const int tid = threadIdx.x;
  const bool valid = tid < 225;
  const int py0 = (tid / 15) * 2;
  const int px0 = (tid % 15) * 2;
  const int br = 2 * py0;
  const int bc = 2 * px0;

  float v[16], cur[16];
#pragma unroll
  for (int j = 0; j < 16; ++j) { v[j] = 0.f; cur[j] = 0.f; }
  const float bias = b1[oc];

  for (int t = 0; t < TT; ++t) {
    const float* xp = x + ((size_t)(t * BB + b)) * 12288;
#pragma unroll
    for (int k = 0; k < 12; ++k) {
      int e = tid + k * 256;           // float4 index in [0,3072)
      int row = e >> 4, c4 = e & 15;
      ((float4*)xs)[row * 17 + c4] = ((const float4*)xp)[e];
    }
    __syncthreads();

    if (valid) {
      float acc[4][4];
#pragma unroll
      for (int r = 0; r < 4; ++r)
#pragma unroll
        for (int s = 0; s < 4; ++s) acc[r][s] = 0.f;

#pragma unroll
      for (int c = 0; c < 3; ++c) {
        const float* wp = w1 + (oc * 3 + c) * 25;
        float wv[25];
#pragma unroll
        for (int j = 0; j < 25; ++j) wv[j] = wp[j];
#pragma unroll
        for (int ri = 0; ri < 8; ++ri) {
          const float* rowp = &xs[(c * 64 + br + ri) * 68 + bc];
          float4 ra = *(const float4*)rowp;
          float4 rb = *(const float4*)(rowp + 4);
          float row[8] = {ra.x, ra.y, ra.z, ra.w, rb.x, rb.y, rb.z, rb.w};
#pragma unroll
          for (int r = 0; r < 4; ++r) {
            int ky = ri - r;
            if (ky >= 0 && ky < 5) {
#pragma unroll
              for (int kx = 0; kx < 5; ++kx) {
                float w = wv[ky * 5 + kx];
#pragma unroll
                for (int s = 0; s < 4; ++s) acc[r][s] += w * row[s + kx];
              }
            }
          }
        }
      }

      unsigned char pz00 = 0, pz01 = 0, pz10 = 0, pz11 = 0;
#pragma unroll
      for (int r = 0; r < 4; ++r)
#pragma unroll
        for (int s = 0; s < 4; ++s) {
          int j = r * 4 + s;
          float vd = v[j] + DT_TM * (cur[j] - v[j]);
          float id = SYN_DEC * cur[j];
          float inp = acc[r][s] + bias;
          bool z = vd > 1.0f;
          v[j] = z ? 0.f : vd;
          cur[j] = id + inp;
          if (z) {
            if (r < 2) { if (s < 2) pz00 = 1; else pz01 = 1; }
            else       { if (s < 2) pz10 = 1; else pz11 = 1; }
          }
        }
      size_t pixb = ((size_t)(t * BB + b)) * 900;
      s1[(pixb + (size_t)py0 * 30 + px0) * 32 + oc]           = pz00;
      s1[(pixb + (size_t)py0 * 30 + px0 + 1) * 32 + oc]       = pz01;
      s1[(pixb + (size_t)(py0 + 1) * 30 + px0) * 32 + oc]     = pz10;
      s1[(pixb + (size_t)(py0 + 1) * 30 + px0 + 1) * 32 + oc] = pz11;
    }
    __syncthreads();
  }
}

// ---------------------------------------------------------------------------
// K2: conv2 via MFMA (bf16 hi/lo split) + *10 + LIF + 2x2 pool, all T.
// Templated on spike-output type: ushort (bf16 one-hot) for BIG path,
// uchar for fallback.
// ---------------------------------------------------------------------------
template<int NT>
__device__ __forceinline__ void k2_wave(
    const unsigned short* sl, float* Vst, float* Ist, unsigned char* zbuf,
    const unsigned short* __restrict__ whi, const unsigned short* __restrict__ wlo,
    const float* __restrict__ b2, int og, int q, int n, int ntstart, int npos) {
  int baddr[NT], pcl[NT];
  f32x4 acc[2][NT];
#pragma unroll
  for (int j = 0; j < NT; ++j) {
    int pl = (ntstart + j) * 16 + n;
    if (pl > npos - 1) pl = npos - 1;
    pcl[j] = pl;
    int ry = pl / 26, xx = pl - ry * 26;
    baddr[j] = (ry * 30 + xx) * 32 + q * 8;
    acc[0][j] = (f32x4){0.f, 0.f, 0.f, 0.f};
    acc[1][j] = (f32x4){0.f, 0.f, 0.f, 0.f};
  }
  const int abase = (og * 32 + n) * 32 + q * 8;
#pragma unroll 5
  for (int kk = 0; kk < 25; ++kk) {
    const int ky = kk / 5, kx = kk - (kk / 5) * 5;
    const int off = (ky * 30 + kx) * 32;
    short8v ah0 = *(const short8v*)(whi + kk * 2048 + abase);
    short8v al0 = *(const short8v*)(wlo + kk * 2048 + abase);
    short8v ah1 = *(const short8v*)(whi + kk * 2048 + abase + 512);
    short8v al1 = *(const short8v*)(wlo + kk * 2048 + abase + 512);
#pragma unroll
    for (int j = 0; j < NT; ++j) {
      short8v bv = *(const short8v*)(sl + baddr[j] + off);
      acc[0][j] = __builtin_amdgcn_mfma_f32_16x16x32_bf16(al0, bv, acc[0][j], 0, 0, 0);
      acc[0][j] = __builtin_amdgcn_mfma_f32_16x16x32_bf16(ah0, bv, acc[0][j], 0, 0, 0);
      acc[1][j] = __builtin_amdgcn_mfma_f32_16x16x32_bf16(al1, bv, acc[1][j], 0, 0, 0);
      acc[1][j] = __builtin_amdgcn_mfma_f32_16x16x32_bf16(ah1, bv, acc[1][j], 0, 0, 0);
    }
  }
  const f32x4 bias0 = *(const f32x4*)&b2[og * 32 + q * 4];
  const f32x4 bias1 = *(const f32x4*)&b2[og * 32 + 16 + q * 4];
#pragma unroll
  for (int j = 0; j < NT; ++j) {
    int p = pcl[j];
#pragma unroll
    for (int mi = 0; mi < 2; ++mi) {
      int sidx = p * 68 + og * 32 + mi * 16 + q * 4;
      f32x4 v4 = *(f32x4*)&Vst[sidx];
      f32x4 i4 = *(f32x4*)&Ist[sidx];
      f32x4 bia = mi ? bias1 : bias0;
      f32x4 a = acc[mi][j];
      unsigned char zr[4];
#pragma unroll
      for (int r = 0; r < 4; ++r) {
        float vd = v4[r] + DT_TM * (i4[r] - v4[r]);
        float id = SYN_DEC * i4[r];
        float inp = 10.f * (a[r] + bia[r]);
        bool z = vd > 1.0f;
        v4[r] = z ? 0.f : vd;
        i4[r] = id + inp;
        zr[r] = z ? 1 : 0;
      }
      *(f32x4*)&Vst[sidx] = v4;
      *(f32x4*)&Ist[sidx] = i4;
      *(uchar4*)&zbuf[sidx] = make_uchar4(zr[0], zr[1], zr[2], zr[3]);
    }
  }
}

template<typename ST>
__global__ __launch_bounds__(256) void k2_mfma(
    const unsigned char* __restrict__ s1, const unsigned short* __restrict__ whi,
    const unsigned short* __restrict__ wlo, const float* __restrict__ b2,
    ST* __restrict__ s2) {
  __shared__ unsigned short sl[12 * 30 * 32];
  __shared__ float Vst[208 * 68];
  __shared__ float Ist[208 * 68];
  __shared__ unsigned char zbuf[208 * 68];
  const int quad = blockIdx.x, b = blockIdx.y;
  const int tid = threadIdx.x;
  const int wid = tid >> 6, l = tid & 63;
  const int og = wid & 1, nc = wid >> 1;
  const int q = l >> 4, n = l & 15;
  const int y0 = (quad == 0) ? 0 : (2 + quad * 6);
  const int R  = (quad == 0) ? 8 : 6;
  const int inRows = R + 4;
  const int npos = R * 26;

  for (int e = tid; e < 208 * 68; e += 256) { Vst[e] = 0.f; Ist[e] = 0.f; }
  __syncthreads();

  for (int t = 0; t < TT; ++t) {
    const unsigned char* sp =
        s1 + (((size_t)(t * BB + b)) * 900 + (size_t)y0 * 30) * 32;
    const int nelem = inRows * 240;
    for (int e = tid; e < nelem; e += 256) {
      unsigned int w = *(const unsigned int*)(sp + (size_t)e * 4);
      unsigned int lo = ((w & 0xFFu) ? 0x3F80u : 0u) |
                        ((w & 0xFF00u) ? 0x3F800000u : 0u);
      unsigned int hi = ((w & 0xFF0000u) ? 0x3F80u : 0u) |
                        ((w & 0xFF000000u) ? 0x3F800000u : 0u);
      ((unsigned int*)sl)[e * 2]     = lo;
      ((unsigned int*)sl)[e * 2 + 1] = hi;
    }
    __syncthreads();

    if (quad == 0) {
      if (nc == 0) k2_wave<7>(sl, Vst, Ist, zbuf, whi, wlo, b2, og, q, n, 0, npos);
      else         k2_wave<6>(sl, Vst, Ist, zbuf, whi, wlo, b2, og, q, n, 7, npos);
    } else {
      k2_wave<5>(sl, Vst, Ist, zbuf, whi, wlo, b2, og, q, n, nc * 5, npos);
    }
    __syncthreads();

    const int pr = R >> 1;
    const int pcount = pr * 13 * 64;
    ST* s2p = s2 + ((size_t)(t * BB + b)) * 64 * 169;
    const int gpy0 = y0 >> 1;
    const ST one = (ST)((sizeof(ST) == 2) ? 0x3F80 : 1);
    for (int e = tid; e < pcount; e += 256) {
      int oc = e & 63, pp = e >> 6;
      int ppy = pp / 13, ppx = pp - ppy * 13;
      int base = (2 * ppy * 26 + 2 * ppx) * 68 + oc;
      unsigned char z = (unsigned char)(zbuf[base] | zbuf[base + 68] |
                        zbuf[base + 26 * 68] | zbuf[base + 26 * 68 + 68]);
      s2p[(size_t)oc * 169 + (gpy0 + ppy) * 13 + ppx] = z ? one : (ST)0;
    }
    __syncthreads();
  }
}

// ---------------------------------------------------------------------------
// K3g (BIG): one-shot FC GEMM, M=1024 (t*64+b), N=1024, K=10816, split-K 4.
// A = s2 bf16 spikes [m][k]; B = whiF/wloF [n][k] (wf native layout).
// Tile 128x128, 8 waves; wave = 64m x 32n; BK=64. part[ks][1024][1024].
// ---------------------------------------------------------------------------
__global__ __launch_bounds__(512) void k3g_fc(
    const unsigned short* __restrict__ s2,
    const unsigned short* __restrict__ whiF,
    const unsigned short* __restrict__ wloF,
    float* __restrict__ part) {
  __shared__ __align__(16) unsigned short As[128][72];
  __shared__ __align__(16) unsigned short Bh[128][72];
  __shared__ __align__(16) unsigned short Bl[128][72];
  const int tid = threadIdx.x;
  const int w = tid >> 6, l = tid & 63;
  const int mh = w & 1, nq = w >> 1;
  const int lr = l & 15, lk = l >> 4;
  const int n0 = blockIdx.x * 128, m0 = blockIdx.y * 128;
  const int ks = blockIdx.z;
  const int s_begin = (169 * ks) >> 2, s_end = (169 * (ks + 1)) >> 2;

  const int arow = tid >> 2, aseg = tid & 3;          // 16 shorts each
  const unsigned short* ap = s2 + (size_t)(m0 + arow) * FCK + aseg * 16;
  unsigned short* aq = &As[0][0] + arow * 72 + aseg * 16;
  const int barr = tid >> 8, brem = tid & 255;
  const int bn = brem >> 1, bhalf = brem & 1;         // 32 shorts each
  const unsigned short* bp =
      (barr ? wloF : whiF) + (size_t)(n0 + bn) * FCK + bhalf * 32;
  unsigned short* bq = (barr ? &Bl[0][0] : &Bh[0][0]) + bn * 72 + bhalf * 32;

  f32x4 acc[4][2];
#pragma unroll
  for (int mt = 0; mt < 4; ++mt)
#pragma unroll
    for (int nt = 0; nt < 2; ++nt) acc[mt][nt] = (f32x4){0.f, 0.f, 0.f, 0.f};

  for (int s = s_begin; s < s_end; ++s) {
    const size_t k0 = (size_t)s * 64;
    short8v a0 = *(const short8v*)(ap + k0);
    short8v a1 = *(const short8v*)(ap + k0 + 8);
    short8v b0 = *(const short8v*)(bp + k0);
    short8v b1 = *(const short8v*)(bp + k0 + 8);
    short8v b2v = *(const short8v*)(bp + k0 + 16);
    short8v b3 = *(const short8v*)(bp + k0 + 24);
    __syncthreads();
    *(short8v*)(aq)      = a0;
    *(short8v*)(aq + 8)  = a1;
    *(short8v*)(bq)      = b0;
    *(short8v*)(bq + 8)  = b1;
    *(short8v*)(bq + 16) = b2v;
    *(short8v*)(bq + 24) = b3;
    __syncthreads();
#pragma unroll
    for (int kt = 0; kt < 2; ++kt) {
      short8v bh0 = *(const short8v*)&Bh[nq * 32 + lr][kt * 32 + lk * 8];
      short8v bh1 = *(const short8v*)&Bh[nq * 32 + 16 + lr][kt * 32 + lk * 8];
      short8v bl0 = *(const short8v*)&Bl[nq * 32 + lr][kt * 32 + lk * 8];
      short8v bl1 = *(const short8v*)&Bl[nq * 32 + 16 + lr][kt * 32 + lk * 8];
#pragma unroll
      for (int mt = 0; mt < 4; ++mt) {
        short8v af = *(const short8v*)&As[mh * 64 + mt * 16 + lr][kt * 32 + lk * 8];
        acc[mt][0] = __builtin_amdgcn_mfma_f32_16x16x32_bf16(af, bh0, acc[mt][0], 0, 0, 0);
        acc[mt][0] = __builtin_amdgcn_mfma_f32_16x16x32_bf16(af, bl0, acc[mt][0], 0, 0, 0);
        acc[mt][1] = __builtin_amdgcn_mfma_f32_16x16x32_bf16(af, bh1, acc[mt][1], 0, 0, 0);
        acc[mt][1] = __builtin_amdgcn_mfma_f32_16x16x32_bf16(af, bl1, acc[mt][1], 0, 0, 0);
      }
    }
  }
  float* pp = part + ((size_t)ks << 20);
#pragma unroll
  for (int mt = 0; mt < 4; ++mt)
#pragma unroll
    for (int nt = 0; nt < 2; ++nt) {
      int mrow = m0 + mh * 64 + mt * 16 + lk * 4;
      int ncol = n0 + nq * 32 + nt * 16 + lr;
#pragma unroll
      for (int r = 0; r < 4; ++r)
        pp[(size_t)(mrow + r) * 1024 + ncol] = acc[mt][nt][r];
    }
}

// K3r (BIG): split-K reduce + bias + LIF2 recurrence over all t, state in regs
__global__ __launch_bounds__(256) void k3r_lif2(
    const float* __restrict__ part, const float* __restrict__ bf,
    float* __restrict__ s3) {
  int e = blockIdx.x * 256 + threadIdx.x;    // b*1024 + n
  int n = e & 1023;
  const float bias = bf[n];
  float v = 0.f, cur = 0.f;
  for (int t = 0; t < TT; ++t) {
    size_t idx = ((size_t)(t * BB) << 10) + e;   // (t*64+b)*1024 + n
    float g = part[idx] + part[idx + (1u << 20)] +
              part[idx + (2u << 20)] + part[idx + (3u << 20)] + bias;
    float vd = v + DT_TM * (cur - v);
    float id = SYN_DEC * cur;
    bool sp = vd > 1.0f;
    v = sp ? 0.f : vd;
    cur = id + g;
    s3[(size_t)t * 65536 + e] = sp ? 1.f : 0.f;
  }
}

// ---------------------------------------------------------------------------
// Fallback K3a/K3b (per-t split-K GEMM on u8 spikes) — R2 path
// ---------------------------------------------------------------------------
__global__ __launch_bounds__(256) void k3a_fc(
    const unsigned char* __restrict__ s2, const float* __restrict__ wf,
    float* __restrict__ part, int t) {
  __shared__ float As[16][68];
  __shared__ float Bs[16][68];
  const int nt = blockIdx.x;
  const int ks = blockIdx.y;
  const int tid = threadIdx.x;
  const int N0 = nt * 64;
  const int kbase = ks * 416;
  const unsigned char* A = s2 + (size_t)t * BB * FCK;

  const int lm = tid >> 2;
  const int kq = tid & 3;
  const int m0 = (tid >> 4) << 2;
  const int n0 = (tid & 15) << 2;

  float acc[4][4];
#pragma unroll
  for (int i = 0; i < 4; ++i)
#pragma unroll
    for (int j = 0; j < 4; ++j) acc[i][j] = 0.f;

  for (int step = 0; step < 26; ++step) {
    int k0 = kbase + step * 16;
    uchar4 a4 = *(const uchar4*)&A[(size_t)lm * FCK + k0 + kq * 4];
    float4 b4 = *(const float4*)&wf[(size_t)(N0 + lm) * FCK + k0 + kq * 4];
    __syncthreads();
    As[kq * 4 + 0][lm] = (float)a4.x;
    As[kq * 4 + 1][lm] = (float)a4.y;
    As[kq * 4 + 2][lm] = (float)a4.z;
    As[kq * 4 + 3][lm] = (float)a4.w;
    Bs[kq * 4 + 0][lm] = b4.x;
    Bs[kq * 4 + 1][lm] = b4.y;
    Bs[kq * 4 + 2][lm] = b4.z;
    Bs[kq * 4 + 3][lm] = b4.w;
    __syncthreads();
#pragma unroll
    for (int kk = 0; kk < 16; ++kk) {
      float4 av = *(const float4*)&As[kk][m0];
      float4 bv = *(const float4*)&Bs[kk][n0];
      float a0 = av.x, a1 = av.y, a2 = av.z, a3 = av.w;
      acc[0][0] += a0 * bv.x; acc[0][1] += a0 * bv.y; acc[0][2] += a0 * bv.z; acc[0][3] += a0 * bv.w;
      acc[1][0] += a1 * bv.x; acc[1][1] += a1 * bv.y; acc[1][2] += a1 * bv.z; acc[1][3] += a1 * bv.w;
      acc[2][0] += a2 * bv.x; acc[2][1] += a2 * bv.y; acc[2][2] += a2 * bv.z; acc[2][3] += a2 * bv.w;
      acc[3][0] += a3 * bv.x; acc[3][1] += a3 * bv.y; acc[3][2] += a3 * bv.z; acc[3][3] += a3 * bv.w;
    }
  }
#pragma unroll
  for (int i = 0; i < 4; ++i)
#pragma unroll
    for (int j = 0; j < 4; ++j)
      part[((size_t)(ks * 64 + m0 + i)) * 1024 + N0 + n0 + j] = acc[i][j];
}

__global__ __launch_bounds__(256) void k3b_lif2(
    const float* __restrict__ part, const float* __restrict__ bf,
    float* __restrict__ v2, float* __restrict__ i2,
    float* __restrict__ s3, int t) {
  int e = blockIdx.x * 256 + threadIdx.x;
  int n = e & 1023;
  float s = 0.f;
#pragma unroll
  for (int ks = 0; ks < 26; ++ks) s += part[(size_t)ks * 65536 + e];
  float z = s + bf[n];
  float vv = v2[e], ii = i2[e];
  float vd = vv + DT_TM * (ii - vv);
  float id = SYN_DEC * ii;
  bool sp = vd > 1.0f;
  v2[e] = sp ? 0.f : vd;
  i2[e] = id + z;
  s3[(size_t)t * 65536 + e] = sp ? 1.f : 0.f;
}

// ---------------------------------------------------------------------------
// K4: readout, LI state in registers. out[t][b][10]
// ---------------------------------------------------------------------------
__global__ __launch_bounds__(320) void k4_out(
    const float* __restrict__ s3, const float* __restrict__ wo,
    const float* __restrict__ bo, float* __restrict__ out) {
  const int b = blockIdx.x;
  const int g = threadIdx.x >> 5;
  const int l = threadIdx.x & 31;
  float vv = 0.f, ii = 0.f;
  const float bg = bo[g];
  for (int t = 0; t < TT; ++t) {
    const float* zp = s3 + ((size_t)t * BB + b) * 1024;
    const float* wp = wo + g * 1024;
    float p = 0.f;
#pragma unroll 8
    for (int j = l; j < 1024; j += 32) p += zp[j] * wp[j];
#pragma unroll
    for (int off = 16; off; off >>= 1) p += __shfl_down(p, off, 32);
    float inp = p + bg;
    float vn = vv + DT_TM * (ii - vv);
    if (l == 0) out[(size_t)(t * BB + b) * 10 + g] = vn;
    ii = SYN_DEC * ii + inp;
    vv = vn;
  }
}

extern "C" void kernel_launch(void* const* d_in, const int* in_sizes, int n_in,
                              void* d_out, int out_size, void* d_ws, size_t ws_size,
                              hipStream_t stream) {
  (void)in_sizes; (void)n_in; (void)out_size;
  const float* x  = (const float*)d_in[0];
  const float* w1 = (const float*)d_in[1];
  const float* b1 = (const float*)d_in[2];
  const float* w2 = (const float*)d_in[3];
  const float* b2 = (const float*)d_in[4];
  const float* wf = (const float*)d_in[5];
  const float* bf = (const float*)d_in[6];
  const float* wo = (const float*)d_in[7];
  const float* bo = (const float*)d_in[8];
  float* out = (float*)d_out;
  char* ws = (char*)d_ws;

  if (ws_size >= BIG_NEED) {
    unsigned char*  s1   = (unsigned char*)(ws + BO_S1);
    unsigned short* s2   = (unsigned short*)(ws + BO_S2);
    float*          s3   = (float*)(ws + BO_S3);
    float*          part = (float*)(ws + BO_PART);
    unsigned short* wh2  = (unsigned short*)(ws + BO_WH2);
    unsigned short* wl2  = (unsigned short*)(ws + BO_WL2);
    unsigned short* whiF = (unsigned short*)(ws + BO_WHF);
    unsigned short* wloF = (unsigned short*)(ws + BO_WLF);

    k0_prep<<<dim3(200), 256, 0, stream>>>(w2, wh2, wl2);
    k0b_wf<<<dim3(43264), 256, 0, stream>>>(wf, whiF, wloF);
    k1_conv1<<<dim3(32, 64), 256, 0, stream>>>(x, w1, b1, s1);
    k2_mfma<unsigned short><<<dim3(4, 64), 256, 0, stream>>>(s1, wh2, wl2, b2, s2);
    k3g_fc<<<dim3(8, 8, 4), 512, 0, stream>>>(s2, whiF, wloF, part);
    k3r_lif2<<<dim3(256), 256, 0, stream>>>(part, bf, s3);
    k4_out<<<dim3(64), 320, 0, stream>>>(s3, wo, bo, out);
  } else {
    unsigned char*  s1   = (unsigned char*)(ws + FO_S1);
    unsigned char*  s2   = (unsigned char*)(ws + FO_S2);
    float*          s3   = (float*)(ws + FO_S3);
    float*          part = (float*)(ws + FO_PART);
    float*          v2   = (float*)(ws + FO_V2);
    float*          i2   = (float*)(ws + FO_I2);
    unsigned short* wh2  = (unsigned short*)(ws + FO_WH2);
    unsigned short* wl2  = (unsigned short*)(ws + FO_WL2);

    hipMemsetAsync(v2, 0, 2 * 65536 * sizeof(float), stream);
    k0_prep<<<dim3(200), 256, 0, stream>>>(w2, wh2, wl2);
    k1_conv1<<<dim3(32, 64), 256, 0, stream>>>(x, w1, b1, s1);
    k2_mfma<unsigned char><<<dim3(4, 64), 256, 0, stream>>>(s1, wh2, wl2, b2, s2);
    for (int t = 0; t < TT; ++t) {
      k3a_fc<<<dim3(16, 26), 256, 0, stream>>>(s2, wf, part, t);
      k3b_lif2<<<dim3(256), 256, 0, stream>>>(part, bf, v2, i2, s3, t);
    }
    k4_out<<<dim3(64), 320, 0, stream>>>(s3, wo, bo, out);
  }
}